// Round 5
// baseline (557.590 us; speedup 1.0000x reference)
//
#include <hip/hip_runtime.h>

#define TPB 256

// ---------------- edge preprocessing: counting sort by dst ----------------

__global__ __launch_bounds__(TPB) void k_zero_i32(int* __restrict__ p, int n) {
  int i = blockIdx.x * TPB + threadIdx.x;
  if (i < n) p[i] = 0;
}

__global__ __launch_bounds__(TPB) void k_hist(int* __restrict__ cnt,
                                              const int* __restrict__ ei,
                                              long long E) {
  long long e = (long long)blockIdx.x * TPB + threadIdx.x;
  if (e < E) atomicAdd(&cnt[ei[E + e]], 1);
}

// per-256-chunk exclusive scan of cnt -> off, chunk totals -> part
__global__ __launch_bounds__(TPB) void k_blockscan(const int* __restrict__ cnt,
                                                   int* __restrict__ off,
                                                   int* __restrict__ part, int n) {
  __shared__ int lds[TPB];
  int gid = blockIdx.x * TPB + threadIdx.x;
  int v = (gid < n) ? cnt[gid] : 0;
  lds[threadIdx.x] = v;
  __syncthreads();
#pragma unroll
  for (int ofs = 1; ofs < TPB; ofs <<= 1) {
    int t = (threadIdx.x >= ofs) ? lds[threadIdx.x - ofs] : 0;
    __syncthreads();
    lds[threadIdx.x] += t;
    __syncthreads();
  }
  int incl = lds[threadIdx.x];
  if (gid < n) off[gid] = incl - v;
  if (threadIdx.x == TPB - 1) part[blockIdx.x] = incl;
}

// single-block exclusive scan of part[B], B <= 512
__global__ __launch_bounds__(512) void k_scanpart(int* __restrict__ part, int B) {
  __shared__ int lds[512];
  int v = (threadIdx.x < B) ? part[threadIdx.x] : 0;
  lds[threadIdx.x] = v;
  __syncthreads();
#pragma unroll
  for (int ofs = 1; ofs < 512; ofs <<= 1) {
    int t = (threadIdx.x >= ofs) ? lds[threadIdx.x - ofs] : 0;
    __syncthreads();
    lds[threadIdx.x] += t;
    __syncthreads();
  }
  if (threadIdx.x < B) part[threadIdx.x] = lds[threadIdx.x] - v;
}

// off += scanned part; pos = off; dinv = rsqrt(1 + cnt)
__global__ __launch_bounds__(TPB) void k_finalize_off(int* __restrict__ off,
                                                      int* __restrict__ pos,
                                                      float* __restrict__ dinv,
                                                      const int* __restrict__ part,
                                                      const int* __restrict__ cnt,
                                                      int n) {
  int gid = blockIdx.x * TPB + threadIdx.x;
  if (gid >= n) return;
  int o = off[gid] + part[blockIdx.x];
  off[gid] = o;
  pos[gid] = o;
  dinv[gid] = rsqrtf(1.0f + (float)cnt[gid]);
}

// scatter each edge's src to its sorted-by-dst slot (4B payload, no gather)
__global__ __launch_bounds__(TPB) void k_scatter_sort(int* __restrict__ pay,
                                                      int* __restrict__ pos,
                                                      const int* __restrict__ ei,
                                                      long long E) {
  long long e = (long long)blockIdx.x * TPB + threadIdx.x;
  if (e >= E) return;
  int s = ei[e];
  int d = ei[E + e];
  int p = atomicAdd(&pos[d], 1);
  pay[p] = s;
}

// ------ dense GEMM: hs[N,128] = dinv * ((relu?)(A)[N,128] @ W[128,128]) -----
// 128x128 tile, 512 threads. Only A staged in LDS (67.5 KB -> 2 blocks/CU,
// 4 waves/SIMD). W read from global: per-wave each W load = 4 distinct
// float4 = one 64B line -> L1 broadcast. A LDS reads: 16 addrs, 2-way bank
// alias (free). Epilogue scales rows by dinv.

template <int RELU>
__global__ __launch_bounds__(512) void k_gemm128(const float* __restrict__ A,
                                                 const float* __restrict__ W,
                                                 const float* __restrict__ dinv,
                                                 float* __restrict__ C, int N) {
  __shared__ float As[128 * 132];        // [r][k], float4 stride 33
  const int tid = threadIdx.x;
  const long long row0 = (long long)blockIdx.x * 128;

  {
    const float4* A4 = (const float4*)A;
    float4* As4 = (float4*)As;
#pragma unroll
    for (int i = 0; i < 8; ++i) {
      int l = i * 512 + tid;
      int r = l >> 5;        // 0..127
      int kq = l & 31;       // float4 index along k
      long long gr = row0 + r;
      float4 v = (gr < (long long)N) ? A4[gr * 32 + kq]
                                     : make_float4(0.f, 0.f, 0.f, 0.f);
      if (RELU) {
        v.x = fmaxf(v.x, 0.f); v.y = fmaxf(v.y, 0.f);
        v.z = fmaxf(v.z, 0.f); v.w = fmaxf(v.w, 0.f);
      }
      As4[r * 33 + kq] = v;
    }
  }
  __syncthreads();

  const int tx = tid & 15;    // rows tx + 16j
  const int ty = tid >> 4;    // float4-col 0..31
  const float4* As4 = (const float4*)As;
  const float4* W4 = (const float4*)W;   // [k][n4]: idx k*32 + n4

  float4 acc[8];
#pragma unroll
  for (int j = 0; j < 8; ++j) acc[j] = make_float4(0.f, 0.f, 0.f, 0.f);

#pragma unroll 2
  for (int kk = 0; kk < 32; ++kk) {      // k in chunks of 4
    float4 a[8];
#pragma unroll
    for (int j = 0; j < 8; ++j) a[j] = As4[(tx + (j << 4)) * 33 + kk];
    float4 w[4];
#pragma unroll
    for (int jj = 0; jj < 4; ++jj) w[jj] = W4[(kk * 4 + jj) * 32 + ty];
#pragma unroll
    for (int jj = 0; jj < 4; ++jj) {
#pragma unroll
      for (int j = 0; j < 8; ++j) {
        const float av = ((const float*)&a[j])[jj];
        acc[j].x = fmaf(av, w[jj].x, acc[j].x);
        acc[j].y = fmaf(av, w[jj].y, acc[j].y);
        acc[j].z = fmaf(av, w[jj].z, acc[j].z);
        acc[j].w = fmaf(av, w[jj].w, acc[j].w);
      }
    }
  }

  float4* C4 = (float4*)C;
#pragma unroll
  for (int j = 0; j < 8; ++j) {
    long long r = row0 + tx + (j << 4);
    if (r < (long long)N) {
      float s = dinv[r];
      float4 o;
      o.x = acc[j].x * s; o.y = acc[j].y * s;
      o.z = acc[j].z * s; o.w = acc[j].w * s;
      C4[r * 32 + ty] = o;
    }
  }
}

// ---------------- gather-reduce aggregation (no atomics) --------------------
// out[i,:] = relu?( b + dinv[i] * ( hs[i,:] + sum_{e: dst=i} hs[src,:] ) )
// one 64-lane wave per node, float2 per lane (no intra-wave pairing waste).
template <int RELU>
__global__ __launch_bounds__(TPB) void k_agg(float2* __restrict__ out,
                                             const float2* __restrict__ hs,
                                             const int* __restrict__ pay,
                                             const int* __restrict__ off,
                                             const int* __restrict__ cnt,
                                             const float* __restrict__ dinv,
                                             const float2* __restrict__ b, int N) {
  long long t = (long long)blockIdx.x * TPB + threadIdx.x;
  int g = (int)(t >> 6);
  if (g >= N) return;
  int c = (int)(t & 63);
  float di = dinv[g];
  float2 bv = b[c];

  float2 acc = hs[(long long)g * 64 + c];   // self-loop term

  int p = off[g];
  const int en = p + cnt[g];

  for (; p + 8 <= en; p += 8) {
    int s[8];
#pragma unroll
    for (int u = 0; u < 8; ++u) s[u] = pay[p + u];
    float2 v[8];
#pragma unroll
    for (int u = 0; u < 8; ++u) v[u] = hs[(long long)s[u] * 64 + c];
#pragma unroll
    for (int u = 0; u < 8; ++u) { acc.x += v[u].x; acc.y += v[u].y; }
  }
  if (p + 4 <= en) {
    int s[4];
#pragma unroll
    for (int u = 0; u < 4; ++u) s[u] = pay[p + u];
    float2 v[4];
#pragma unroll
    for (int u = 0; u < 4; ++u) v[u] = hs[(long long)s[u] * 64 + c];
#pragma unroll
    for (int u = 0; u < 4; ++u) { acc.x += v[u].x; acc.y += v[u].y; }
    p += 4;
  }
  for (; p < en; ++p) {
    float2 v = hs[(long long)pay[p] * 64 + c];
    acc.x += v.x; acc.y += v.y;
  }

  float2 o;
  o.x = fmaf(acc.x, di, bv.x);
  o.y = fmaf(acc.y, di, bv.y);
  if (RELU) { o.x = fmaxf(o.x, 0.f); o.y = fmaxf(o.y, 0.f); }
  out[(long long)g * 64 + c] = o;
}

// ---------------------------------------------------------------------------

extern "C" void kernel_launch(void* const* d_in, const int* in_sizes, int n_in,
                              void* d_out, int out_size, void* d_ws, size_t ws_size,
                              hipStream_t stream) {
  const float* x  = (const float*)d_in[0];
  const float* W1 = (const float*)d_in[1];
  const float* b1 = (const float*)d_in[2];
  const float* W2 = (const float*)d_in[3];
  const float* b2 = (const float*)d_in[4];
  const int*   ei = (const int*)d_in[5];   // [2,E] int32

  const int N = in_sizes[0] / 128;
  const long long E = in_sizes[5] / 2;

  // ws layout
  char* w = (char*)d_ws;
  int*   cnt  = (int*)w;                 w += (size_t)N * 4;
  int*   off  = (int*)w;                 w += (size_t)N * 4;
  int*   pos  = (int*)w;                 w += (size_t)N * 4;
  float* dinv = (float*)w;               w += (size_t)N * 4;
  int*   part = (int*)w;                 w += 2048 * 4;
  int*   pay  = (int*)w;                 w += (size_t)E * 4;
  float* hs   = (float*)w;               // N*128 floats (dinv-prescaled h)

  float* out = (float*)d_out;

  const int gN  = (N + TPB - 1) / TPB;           // 391
  const int gE  = (int)((E + TPB - 1) / TPB);
  const long long n64 = (long long)N * 64;
  const int gN64 = (int)((n64 + TPB - 1) / TPB);
  const int gGemm = (N + 127) / 128;

  // ---- counting sort of edges by dst ----
  k_zero_i32<<<gN, TPB, 0, stream>>>(cnt, N);
  k_hist<<<gE, TPB, 0, stream>>>(cnt, ei, E);
  k_blockscan<<<gN, TPB, 0, stream>>>(cnt, off, part, N);
  k_scanpart<<<1, 512, 0, stream>>>(part, gN);
  k_finalize_off<<<gN, TPB, 0, stream>>>(off, pos, dinv, part, cnt, N);
  k_scatter_sort<<<gE, TPB, 0, stream>>>(pay, pos, ei, E);

  // ---- layer 1: hs = dinv*(x@W1) ; out = b1 + dinv*(hs_i + sum hs_src) ----
  k_gemm128<0><<<gGemm, 512, 0, stream>>>(x, W1, dinv, hs, N);
  k_agg<0><<<gN64, TPB, 0, stream>>>((float2*)out, (const float2*)hs, pay, off,
                                     cnt, dinv, (const float2*)b1, N);

  // ---- layer 2: hs = dinv*(relu(out)@W2) ; out = relu(b2 + dinv*(...)) ----
  k_gemm128<1><<<gGemm, 512, 0, stream>>>(out, W2, dinv, hs, N);
  k_agg<1><<<gN64, TPB, 0, stream>>>((float2*)out, (const float2*)hs, pay, off,
                                     cnt, dinv, (const float2*)b2, N);
}

// Round 6
// 458.668 us; speedup vs baseline: 1.2157x; 1.2157x over previous
//
#include <hip/hip_runtime.h>

#define TPB 256
#define CHA 16384   // edges per k_binA block

// ---------------- small utils ----------------

__global__ __launch_bounds__(TPB) void k_zero_i32(int* __restrict__ p, int n) {
  int i = blockIdx.x * TPB + threadIdx.x;
  if (i < n) p[i] = 0;
}

// ---------------- bucket-level histogram (bucket = dst >> 8) ---------------

__global__ __launch_bounds__(TPB) void k_bucket_hist(int* __restrict__ bc,
                                                     const int* __restrict__ ei,
                                                     long long E, int NB) {
  __shared__ int h[512];
  for (int i = threadIdx.x; i < 512; i += TPB) h[i] = 0;
  __syncthreads();
  long long stride = (long long)gridDim.x * TPB;
  for (long long e = (long long)blockIdx.x * TPB + threadIdx.x; e < E; e += stride)
    atomicAdd(&h[ei[E + e] >> 8], 1);
  __syncthreads();
  for (int i = threadIdx.x; i < NB; i += TPB)
    if (h[i]) atomicAdd(&bc[i], h[i]);
}

// exclusive scan of bc[NB] -> bbase[0..NB], bcursor = bbase (NB <= 512)
__global__ __launch_bounds__(512) void k_scan_buckets(int* __restrict__ bbase,
                                                      int* __restrict__ bcursor,
                                                      const int* __restrict__ bc,
                                                      int NB) {
  __shared__ int lds[512];
  int v = (threadIdx.x < NB) ? bc[threadIdx.x] : 0;
  lds[threadIdx.x] = v;
  __syncthreads();
  for (int ofs = 1; ofs < 512; ofs <<= 1) {
    int t = (threadIdx.x >= ofs) ? lds[threadIdx.x - ofs] : 0;
    __syncthreads();
    lds[threadIdx.x] += t;
    __syncthreads();
  }
  int excl = lds[threadIdx.x] - v;
  if (threadIdx.x < NB) { bbase[threadIdx.x] = excl; bcursor[threadIdx.x] = excl; }
  if (threadIdx.x == NB - 1) bbase[NB] = excl + v;
}

// ---------------- pass A: bin edges into buckets, LDS-staged ----------------
// key = (src << 8) | (dst & 255); runs written bucket-contiguously.
__global__ __launch_bounds__(TPB) void k_binA(unsigned* __restrict__ keys,
                                              int* __restrict__ bcursor,
                                              const int* __restrict__ ei,
                                              long long E, int NB) {
  __shared__ int hist[512];
  __shared__ int scanv[512];
  __shared__ int base_run[512];
  __shared__ int bump[512];
  __shared__ unsigned stage[CHA];   // 64 KB

  const int tid = threadIdx.x;
  const long long e0 = (long long)blockIdx.x * CHA;
  const int cnt_here = (int)min((long long)CHA, E - e0);

  for (int i = tid; i < 512; i += TPB) { hist[i] = 0; bump[i] = 0; }
  __syncthreads();

  for (int i = tid; i < cnt_here; i += TPB)
    atomicAdd(&hist[ei[E + e0 + i] >> 8], 1);
  __syncthreads();

  // exclusive scan of hist[512] with 256 threads (2 elems each)
  int a0 = hist[tid], a1 = hist[tid + 256];
  scanv[tid] = a0; scanv[tid + 256] = a1;
  __syncthreads();
  for (int ofs = 1; ofs < 512; ofs <<= 1) {
    int t0 = (tid >= ofs) ? scanv[tid - ofs] : 0;
    int t1 = (tid + 256 >= ofs) ? scanv[tid + 256 - ofs] : 0;
    __syncthreads();
    scanv[tid] += t0; scanv[tid + 256] += t1;
    __syncthreads();
  }
  scanv[tid] -= a0; scanv[tid + 256] -= a1;

  // reserve global runs (one atomic per non-empty bucket)
  for (int i = tid; i < NB; i += TPB) {
    int c = hist[i];
    base_run[i] = c ? atomicAdd(&bcursor[i], c) : 0;
  }
  __syncthreads();

  // scatter into LDS stage, bucket-contiguous
  for (int i = tid; i < cnt_here; i += TPB) {
    int s = ei[e0 + i];
    int d = ei[E + e0 + i];
    int b = d >> 8;
    int r = atomicAdd(&bump[b], 1);
    stage[scanv[b] + r] = ((unsigned)s << 8) | (unsigned)(d & 255);
  }
  __syncthreads();

  // write runs coalesced: wave w takes buckets w, w+4, ...
  const int wave = tid >> 6, lane = tid & 63;
  for (int b = wave; b < NB; b += 4) {
    int s0 = scanv[b], c = hist[b], gbase = base_run[b];
    for (int j = lane; j < c; j += 64) keys[gbase + j] = stage[s0 + j];
  }
}

// ---------------- pass B: per-bucket counting sort + CSR emit ---------------
// block b owns nodes [b*256, b*256+256) and edge region [bbase[b], bbase[b+1]).
__global__ __launch_bounds__(TPB) void k_binB(int* __restrict__ pay,
                                              int* __restrict__ cnt,
                                              int* __restrict__ off,
                                              float* __restrict__ dinv,
                                              const unsigned* __restrict__ keys,
                                              const int* __restrict__ bbase,
                                              int N) {
  __shared__ int lcnt[256], lofs[256], lcur[256];
  const int tid = threadIdx.x;
  const int b = blockIdx.x;
  const int lo = bbase[b], hi = bbase[b + 1];

  lcnt[tid] = 0; lcur[tid] = 0;
  __syncthreads();
  for (int i = lo + tid; i < hi; i += TPB)
    atomicAdd(&lcnt[keys[i] & 255], 1);
  __syncthreads();

  int v = lcnt[tid];
  lofs[tid] = v;
  __syncthreads();
  for (int ofs = 1; ofs < 256; ofs <<= 1) {
    int t = (tid >= ofs) ? lofs[tid - ofs] : 0;
    __syncthreads();
    lofs[tid] += t;
    __syncthreads();
  }
  lofs[tid] -= v;   // exclusive
  __syncthreads();

  const int node = (b << 8) + tid;
  if (node < N) {
    cnt[node] = v;
    off[node] = lo + lofs[tid];
    dinv[node] = rsqrtf(1.0f + (float)v);
  }

  // place srcs; writes random 4B but confined to this block's 16KB region
  for (int i = lo + tid; i < hi; i += TPB) {
    unsigned k = keys[i];
    int l = (int)(k & 255u);
    int r = atomicAdd(&lcur[l], 1);
    pay[lo + lofs[l] + r] = (int)(k >> 8);
  }
}

// ------ dense GEMM: hs[N,128] = dinv * ((relu?)(A)[N,128] @ W[128,128]) -----
// 128x128 tile, 512 threads, only A in LDS (67.5 KB -> 2 blocks/CU);
// W per-wave = one 64B line -> L1 broadcast.
template <int RELU>
__global__ __launch_bounds__(512) void k_gemm128(const float* __restrict__ A,
                                                 const float* __restrict__ W,
                                                 const float* __restrict__ dinv,
                                                 float* __restrict__ C, int N) {
  __shared__ float As[128 * 132];        // [r][k], float4 stride 33
  const int tid = threadIdx.x;
  const long long row0 = (long long)blockIdx.x * 128;

  {
    const float4* A4 = (const float4*)A;
    float4* As4 = (float4*)As;
#pragma unroll
    for (int i = 0; i < 8; ++i) {
      int l = i * 512 + tid;
      int r = l >> 5;
      int kq = l & 31;
      long long gr = row0 + r;
      float4 v = (gr < (long long)N) ? A4[gr * 32 + kq]
                                     : make_float4(0.f, 0.f, 0.f, 0.f);
      if (RELU) {
        v.x = fmaxf(v.x, 0.f); v.y = fmaxf(v.y, 0.f);
        v.z = fmaxf(v.z, 0.f); v.w = fmaxf(v.w, 0.f);
      }
      As4[r * 33 + kq] = v;
    }
  }
  __syncthreads();

  const int tx = tid & 15;
  const int ty = tid >> 4;
  const float4* As4 = (const float4*)As;
  const float4* W4 = (const float4*)W;

  float4 acc[8];
#pragma unroll
  for (int j = 0; j < 8; ++j) acc[j] = make_float4(0.f, 0.f, 0.f, 0.f);

#pragma unroll 2
  for (int kk = 0; kk < 32; ++kk) {
    float4 a[8];
#pragma unroll
    for (int j = 0; j < 8; ++j) a[j] = As4[(tx + (j << 4)) * 33 + kk];
    float4 w[4];
#pragma unroll
    for (int jj = 0; jj < 4; ++jj) w[jj] = W4[(kk * 4 + jj) * 32 + ty];
#pragma unroll
    for (int jj = 0; jj < 4; ++jj) {
#pragma unroll
      for (int j = 0; j < 8; ++j) {
        const float av = ((const float*)&a[j])[jj];
        acc[j].x = fmaf(av, w[jj].x, acc[j].x);
        acc[j].y = fmaf(av, w[jj].y, acc[j].y);
        acc[j].z = fmaf(av, w[jj].z, acc[j].z);
        acc[j].w = fmaf(av, w[jj].w, acc[j].w);
      }
    }
  }

  float4* C4 = (float4*)C;
#pragma unroll
  for (int j = 0; j < 8; ++j) {
    long long r = row0 + tx + (j << 4);
    if (r < (long long)N) {
      float s = dinv[r];
      float4 o;
      o.x = acc[j].x * s; o.y = acc[j].y * s;
      o.z = acc[j].z * s; o.w = acc[j].w * s;
      C4[r * 32 + ty] = o;
    }
  }
}

// ---------------- gather-reduce aggregation (no atomics) --------------------
// out[i,:] = relu?( b + dinv[i] * ( hs[i,:] + sum_{e: dst=i} hs[src,:] ) )
// 32-lane group per node, float4 per lane, 8-deep unrolled gathers.
template <int RELU>
__global__ __launch_bounds__(TPB) void k_agg(float4* __restrict__ out,
                                             const float4* __restrict__ hs,
                                             const int* __restrict__ pay,
                                             const int* __restrict__ off,
                                             const int* __restrict__ cnt,
                                             const float* __restrict__ dinv,
                                             const float4* __restrict__ b, int N) {
  long long t = (long long)blockIdx.x * TPB + threadIdx.x;
  int g = (int)(t >> 5);
  if (g >= N) return;
  int c = (int)(t & 31);
  float di = dinv[g];
  float4 bv = b[c];

  float4 acc = hs[(long long)g * 32 + c];   // self-loop term (prescaled)

  int p = off[g];
  const int en = p + cnt[g];

  for (; p + 8 <= en; p += 8) {
    int s[8];
#pragma unroll
    for (int u = 0; u < 8; ++u) s[u] = pay[p + u];
    float4 v[8];
#pragma unroll
    for (int u = 0; u < 8; ++u) v[u] = hs[(long long)s[u] * 32 + c];
#pragma unroll
    for (int u = 0; u < 8; ++u) {
      acc.x += v[u].x; acc.y += v[u].y; acc.z += v[u].z; acc.w += v[u].w;
    }
  }
  if (p + 4 <= en) {
    int s[4];
#pragma unroll
    for (int u = 0; u < 4; ++u) s[u] = pay[p + u];
    float4 v[4];
#pragma unroll
    for (int u = 0; u < 4; ++u) v[u] = hs[(long long)s[u] * 32 + c];
#pragma unroll
    for (int u = 0; u < 4; ++u) {
      acc.x += v[u].x; acc.y += v[u].y; acc.z += v[u].z; acc.w += v[u].w;
    }
    p += 4;
  }
  for (; p < en; ++p) {
    float4 v = hs[(long long)pay[p] * 32 + c];
    acc.x += v.x; acc.y += v.y; acc.z += v.z; acc.w += v.w;
  }

  float4 o;
  o.x = fmaf(acc.x, di, bv.x);
  o.y = fmaf(acc.y, di, bv.y);
  o.z = fmaf(acc.z, di, bv.z);
  o.w = fmaf(acc.w, di, bv.w);
  if (RELU) {
    o.x = fmaxf(o.x, 0.f); o.y = fmaxf(o.y, 0.f);
    o.z = fmaxf(o.z, 0.f); o.w = fmaxf(o.w, 0.f);
  }
  out[(long long)g * 32 + c] = o;
}

// ---------------------------------------------------------------------------

extern "C" void kernel_launch(void* const* d_in, const int* in_sizes, int n_in,
                              void* d_out, int out_size, void* d_ws, size_t ws_size,
                              hipStream_t stream) {
  const float* x  = (const float*)d_in[0];
  const float* W1 = (const float*)d_in[1];
  const float* b1 = (const float*)d_in[2];
  const float* W2 = (const float*)d_in[3];
  const float* b2 = (const float*)d_in[4];
  const int*   ei = (const int*)d_in[5];   // [2,E] int32

  const int N = in_sizes[0] / 128;
  const long long E = in_sizes[5] / 2;
  const int NB = (N + 255) >> 8;           // buckets of 256 nodes (<= 512)

  // ws layout (hs first for 16B alignment)
  char* w = (char*)d_ws;
  float*    hs      = (float*)w;           w += (size_t)N * 128 * 4;
  int*      pay     = (int*)w;             w += (size_t)E * 4;
  unsigned* keys    = (unsigned*)w;        w += (size_t)E * 4;
  int*      cnt     = (int*)w;             w += (size_t)N * 4;
  int*      off     = (int*)w;             w += (size_t)N * 4;
  float*    dinv    = (float*)w;           w += (size_t)N * 4;
  int*      bc      = (int*)w;             w += (size_t)NB * 4;
  int*      bbase   = (int*)w;             w += (size_t)(NB + 1) * 4;
  int*      bcursor = (int*)w;

  float* out = (float*)d_out;

  const long long n32 = (long long)N * 32;
  const int gN32 = (int)((n32 + TPB - 1) / TPB);
  const int gGemm = (N + 127) / 128;
  const int gBinA = (int)((E + CHA - 1) / CHA);

  // ---- binned counting sort by dst + CSR/dinv emit ----
  k_zero_i32<<<(NB + TPB - 1) / TPB, TPB, 0, stream>>>(bc, NB);
  k_bucket_hist<<<1024, TPB, 0, stream>>>(bc, ei, E, NB);
  k_scan_buckets<<<1, 512, 0, stream>>>(bbase, bcursor, bc, NB);
  k_binA<<<gBinA, TPB, 0, stream>>>(keys, bcursor, ei, E, NB);
  k_binB<<<NB, TPB, 0, stream>>>(pay, cnt, off, dinv, keys, bbase, N);

  // ---- layer 1: hs = dinv*(x@W1) ; out = b1 + dinv*(hs_i + sum hs_src) ----
  k_gemm128<0><<<gGemm, 512, 0, stream>>>(x, W1, dinv, hs, N);
  k_agg<0><<<gN32, TPB, 0, stream>>>((float4*)out, (const float4*)hs, pay, off,
                                     cnt, dinv, (const float4*)b1, N);

  // ---- layer 2: hs = dinv*(relu(out)@W2) ; out = relu(b2 + dinv*(...)) ----
  k_gemm128<1><<<gGemm, 512, 0, stream>>>(out, W2, dinv, hs, N);
  k_agg<1><<<gN32, TPB, 0, stream>>>((float4*)out, (const float4*)hs, pay, off,
                                     cnt, dinv, (const float4*)b2, N);
}

// Round 7
// 341.438 us; speedup vs baseline: 1.6331x; 1.3433x over previous
//
#include <hip/hip_runtime.h>

#define TPB 256
#define CHA 16384   // edges per k_binA block

typedef _Float16 half4 __attribute__((ext_vector_type(4)));   // 8 bytes

// ---------------- small utils ----------------

__global__ __launch_bounds__(TPB) void k_zero_i32(int* __restrict__ p, int n) {
  int i = blockIdx.x * TPB + threadIdx.x;
  if (i < n) p[i] = 0;
}

// ---------------- bucket-level histogram (bucket = dst >> 8) ---------------

__global__ __launch_bounds__(TPB) void k_bucket_hist(int* __restrict__ bc,
                                                     const int* __restrict__ ei,
                                                     long long E, int NB) {
  __shared__ int h[512];
  for (int i = threadIdx.x; i < 512; i += TPB) h[i] = 0;
  __syncthreads();
  long long stride = (long long)gridDim.x * TPB;
  for (long long e = (long long)blockIdx.x * TPB + threadIdx.x; e < E; e += stride)
    atomicAdd(&h[ei[E + e] >> 8], 1);
  __syncthreads();
  for (int i = threadIdx.x; i < NB; i += TPB)
    if (h[i]) atomicAdd(&bc[i], h[i]);
}

// exclusive scan of bc[NB] -> bbase[0..NB], bcursor = bbase (NB <= 512)
__global__ __launch_bounds__(512) void k_scan_buckets(int* __restrict__ bbase,
                                                      int* __restrict__ bcursor,
                                                      const int* __restrict__ bc,
                                                      int NB) {
  __shared__ int lds[512];
  int v = (threadIdx.x < NB) ? bc[threadIdx.x] : 0;
  lds[threadIdx.x] = v;
  __syncthreads();
  for (int ofs = 1; ofs < 512; ofs <<= 1) {
    int t = (threadIdx.x >= ofs) ? lds[threadIdx.x - ofs] : 0;
    __syncthreads();
    lds[threadIdx.x] += t;
    __syncthreads();
  }
  int excl = lds[threadIdx.x] - v;
  if (threadIdx.x < NB) { bbase[threadIdx.x] = excl; bcursor[threadIdx.x] = excl; }
  if (threadIdx.x == NB - 1) bbase[NB] = excl + v;
}

// ---------------- pass A: bin edges into buckets, LDS-staged ----------------
// key = (src << 8) | (dst & 255); runs written bucket-contiguously.
__global__ __launch_bounds__(TPB) void k_binA(unsigned* __restrict__ keys,
                                              int* __restrict__ bcursor,
                                              const int* __restrict__ ei,
                                              long long E, int NB) {
  __shared__ int hist[512];
  __shared__ int scanv[512];
  __shared__ int base_run[512];
  __shared__ int bump[512];
  __shared__ unsigned stage[CHA];   // 64 KB

  const int tid = threadIdx.x;
  const long long e0 = (long long)blockIdx.x * CHA;
  const int cnt_here = (int)min((long long)CHA, E - e0);

  for (int i = tid; i < 512; i += TPB) { hist[i] = 0; bump[i] = 0; }
  __syncthreads();

  for (int i = tid; i < cnt_here; i += TPB)
    atomicAdd(&hist[ei[E + e0 + i] >> 8], 1);
  __syncthreads();

  // exclusive scan of hist[512] with 256 threads (2 elems each)
  int a0 = hist[tid], a1 = hist[tid + 256];
  scanv[tid] = a0; scanv[tid + 256] = a1;
  __syncthreads();
  for (int ofs = 1; ofs < 512; ofs <<= 1) {
    int t0 = (tid >= ofs) ? scanv[tid - ofs] : 0;
    int t1 = (tid + 256 >= ofs) ? scanv[tid + 256 - ofs] : 0;
    __syncthreads();
    scanv[tid] += t0; scanv[tid + 256] += t1;
    __syncthreads();
  }
  scanv[tid] -= a0; scanv[tid + 256] -= a1;

  // reserve global runs (one atomic per non-empty bucket)
  for (int i = tid; i < NB; i += TPB) {
    int c = hist[i];
    base_run[i] = c ? atomicAdd(&bcursor[i], c) : 0;
  }
  __syncthreads();

  // scatter into LDS stage, bucket-contiguous
  for (int i = tid; i < cnt_here; i += TPB) {
    int s = ei[e0 + i];
    int d = ei[E + e0 + i];
    int b = d >> 8;
    int r = atomicAdd(&bump[b], 1);
    stage[scanv[b] + r] = ((unsigned)s << 8) | (unsigned)(d & 255);
  }
  __syncthreads();

  // write runs coalesced: wave w takes buckets w, w+4, ...
  const int wave = tid >> 6, lane = tid & 63;
  for (int b = wave; b < NB; b += 4) {
    int s0 = scanv[b], c = hist[b], gbase = base_run[b];
    for (int j = lane; j < c; j += 64) keys[gbase + j] = stage[s0 + j];
  }
}

// ---------------- pass B: per-bucket counting sort + CSR emit ---------------
// block b owns nodes [b*256, b*256+256) and edge region [bbase[b], bbase[b+1]).
__global__ __launch_bounds__(TPB) void k_binB(int* __restrict__ pay,
                                              int* __restrict__ cnt,
                                              int* __restrict__ off,
                                              float* __restrict__ dinv,
                                              const unsigned* __restrict__ keys,
                                              const int* __restrict__ bbase,
                                              int N) {
  __shared__ int lcnt[256], lofs[256], lcur[256];
  const int tid = threadIdx.x;
  const int b = blockIdx.x;
  const int lo = bbase[b], hi = bbase[b + 1];

  lcnt[tid] = 0; lcur[tid] = 0;
  __syncthreads();
  for (int i = lo + tid; i < hi; i += TPB)
    atomicAdd(&lcnt[keys[i] & 255], 1);
  __syncthreads();

  int v = lcnt[tid];
  lofs[tid] = v;
  __syncthreads();
  for (int ofs = 1; ofs < 256; ofs <<= 1) {
    int t = (tid >= ofs) ? lofs[tid - ofs] : 0;
    __syncthreads();
    lofs[tid] += t;
    __syncthreads();
  }
  lofs[tid] -= v;   // exclusive
  __syncthreads();

  const int node = (b << 8) + tid;
  if (node < N) {
    cnt[node] = v;
    off[node] = lo + lofs[tid];
    dinv[node] = rsqrtf(1.0f + (float)v);
  }

  // place srcs; writes random 4B but confined to this block's 16KB region
  for (int i = lo + tid; i < hi; i += TPB) {
    unsigned k = keys[i];
    int l = (int)(k & 255u);
    int r = atomicAdd(&lcur[l], 1);
    pay[lo + lofs[l] + r] = (int)(k >> 8);
  }
}

// -- dense GEMM: hs[N,128](fp16) = dinv * ((relu?)(A)[N,128] @ W[128,128]) ---
// 128x128 tile, 512 threads, only A in LDS (67.5 KB -> 2 blocks/CU);
// W per-wave = one 64B line -> L1 broadcast. Epilogue: scale by dinv, cvt fp16.
template <int RELU>
__global__ __launch_bounds__(512) void k_gemm128(const float* __restrict__ A,
                                                 const float* __restrict__ W,
                                                 const float* __restrict__ dinv,
                                                 half4* __restrict__ C, int N) {
  __shared__ float As[128 * 132];        // [r][k], float4 stride 33
  const int tid = threadIdx.x;
  const long long row0 = (long long)blockIdx.x * 128;

  {
    const float4* A4 = (const float4*)A;
    float4* As4 = (float4*)As;
#pragma unroll
    for (int i = 0; i < 8; ++i) {
      int l = i * 512 + tid;
      int r = l >> 5;
      int kq = l & 31;
      long long gr = row0 + r;
      float4 v = (gr < (long long)N) ? A4[gr * 32 + kq]
                                     : make_float4(0.f, 0.f, 0.f, 0.f);
      if (RELU) {
        v.x = fmaxf(v.x, 0.f); v.y = fmaxf(v.y, 0.f);
        v.z = fmaxf(v.z, 0.f); v.w = fmaxf(v.w, 0.f);
      }
      As4[r * 33 + kq] = v;
    }
  }
  __syncthreads();

  const int tx = tid & 15;
  const int ty = tid >> 4;
  const float4* As4 = (const float4*)As;
  const float4* W4 = (const float4*)W;

  float4 acc[8];
#pragma unroll
  for (int j = 0; j < 8; ++j) acc[j] = make_float4(0.f, 0.f, 0.f, 0.f);

#pragma unroll 2
  for (int kk = 0; kk < 32; ++kk) {
    float4 a[8];
#pragma unroll
    for (int j = 0; j < 8; ++j) a[j] = As4[(tx + (j << 4)) * 33 + kk];
    float4 w[4];
#pragma unroll
    for (int jj = 0; jj < 4; ++jj) w[jj] = W4[(kk * 4 + jj) * 32 + ty];
#pragma unroll
    for (int jj = 0; jj < 4; ++jj) {
#pragma unroll
      for (int j = 0; j < 8; ++j) {
        const float av = ((const float*)&a[j])[jj];
        acc[j].x = fmaf(av, w[jj].x, acc[j].x);
        acc[j].y = fmaf(av, w[jj].y, acc[j].y);
        acc[j].z = fmaf(av, w[jj].z, acc[j].z);
        acc[j].w = fmaf(av, w[jj].w, acc[j].w);
      }
    }
  }

#pragma unroll
  for (int j = 0; j < 8; ++j) {
    long long r = row0 + tx + (j << 4);
    if (r < (long long)N) {
      float s = dinv[r];
      half4 o;
      o.x = (_Float16)(acc[j].x * s);
      o.y = (_Float16)(acc[j].y * s);
      o.z = (_Float16)(acc[j].z * s);
      o.w = (_Float16)(acc[j].w * s);
      C[r * 32 + ty] = o;
    }
  }
}

// ---------------- gather-reduce aggregation (no atomics) --------------------
// out[i,:] = relu?( b + dinv[i] * ( hs[i,:] + sum_{e: dst=i} hs[src,:] ) )
// 32-lane group per node; hs rows are fp16 (256B), half4 (8B) per lane;
// f32 accumulation; 8-deep unrolled gathers.
template <int RELU>
__global__ __launch_bounds__(TPB) void k_agg(float4* __restrict__ out,
                                             const half4* __restrict__ hs,
                                             const int* __restrict__ pay,
                                             const int* __restrict__ off,
                                             const int* __restrict__ cnt,
                                             const float* __restrict__ dinv,
                                             const float4* __restrict__ b, int N) {
  long long t = (long long)blockIdx.x * TPB + threadIdx.x;
  int g = (int)(t >> 5);
  if (g >= N) return;
  int c = (int)(t & 31);
  float di = dinv[g];
  float4 bv = b[c];

  half4 hv = hs[(long long)g * 32 + c];   // self-loop term (prescaled)
  float4 acc;
  acc.x = (float)hv.x; acc.y = (float)hv.y;
  acc.z = (float)hv.z; acc.w = (float)hv.w;

  int p = off[g];
  const int en = p + cnt[g];

  for (; p + 8 <= en; p += 8) {
    int s[8];
#pragma unroll
    for (int u = 0; u < 8; ++u) s[u] = pay[p + u];
    half4 v[8];
#pragma unroll
    for (int u = 0; u < 8; ++u) v[u] = hs[(long long)s[u] * 32 + c];
#pragma unroll
    for (int u = 0; u < 8; ++u) {
      acc.x += (float)v[u].x; acc.y += (float)v[u].y;
      acc.z += (float)v[u].z; acc.w += (float)v[u].w;
    }
  }
  if (p + 4 <= en) {
    int s[4];
#pragma unroll
    for (int u = 0; u < 4; ++u) s[u] = pay[p + u];
    half4 v[4];
#pragma unroll
    for (int u = 0; u < 4; ++u) v[u] = hs[(long long)s[u] * 32 + c];
#pragma unroll
    for (int u = 0; u < 4; ++u) {
      acc.x += (float)v[u].x; acc.y += (float)v[u].y;
      acc.z += (float)v[u].z; acc.w += (float)v[u].w;
    }
    p += 4;
  }
  for (; p < en; ++p) {
    half4 v = hs[(long long)pay[p] * 32 + c];
    acc.x += (float)v.x; acc.y += (float)v.y;
    acc.z += (float)v.z; acc.w += (float)v.w;
  }

  float4 o;
  o.x = fmaf(acc.x, di, bv.x);
  o.y = fmaf(acc.y, di, bv.y);
  o.z = fmaf(acc.z, di, bv.z);
  o.w = fmaf(acc.w, di, bv.w);
  if (RELU) {
    o.x = fmaxf(o.x, 0.f); o.y = fmaxf(o.y, 0.f);
    o.z = fmaxf(o.z, 0.f); o.w = fmaxf(o.w, 0.f);
  }
  out[(long long)g * 32 + c] = o;
}

// ---------------------------------------------------------------------------

extern "C" void kernel_launch(void* const* d_in, const int* in_sizes, int n_in,
                              void* d_out, int out_size, void* d_ws, size_t ws_size,
                              hipStream_t stream) {
  const float* x  = (const float*)d_in[0];
  const float* W1 = (const float*)d_in[1];
  const float* b1 = (const float*)d_in[2];
  const float* W2 = (const float*)d_in[3];
  const float* b2 = (const float*)d_in[4];
  const int*   ei = (const int*)d_in[5];   // [2,E] int32

  const int N = in_sizes[0] / 128;
  const long long E = in_sizes[5] / 2;
  const int NB = (N + 255) >> 8;           // buckets of 256 nodes (<= 512)

  // ws layout (hs first, 16B-aligned)
  char* w = (char*)d_ws;
  half4*    hs      = (half4*)w;           w += (size_t)N * 128 * 2;
  int*      pay     = (int*)w;             w += (size_t)E * 4;
  unsigned* keys    = (unsigned*)w;        w += (size_t)E * 4;
  int*      cnt     = (int*)w;             w += (size_t)N * 4;
  int*      off     = (int*)w;             w += (size_t)N * 4;
  float*    dinv    = (float*)w;           w += (size_t)N * 4;
  int*      bc      = (int*)w;             w += (size_t)NB * 4;
  int*      bbase   = (int*)w;             w += (size_t)(NB + 1) * 4;
  int*      bcursor = (int*)w;

  float* out = (float*)d_out;

  const long long n32 = (long long)N * 32;
  const int gN32 = (int)((n32 + TPB - 1) / TPB);
  const int gGemm = (N + 127) / 128;
  const int gBinA = (int)((E + CHA - 1) / CHA);

  // ---- binned counting sort by dst + CSR/dinv emit ----
  k_zero_i32<<<(NB + TPB - 1) / TPB, TPB, 0, stream>>>(bc, NB);
  k_bucket_hist<<<1024, TPB, 0, stream>>>(bc, ei, E, NB);
  k_scan_buckets<<<1, 512, 0, stream>>>(bbase, bcursor, bc, NB);
  k_binA<<<gBinA, TPB, 0, stream>>>(keys, bcursor, ei, E, NB);
  k_binB<<<NB, TPB, 0, stream>>>(pay, cnt, off, dinv, keys, bbase, N);

  // ---- layer 1: hs = fp16(dinv*(x@W1)) ; out = b1 + dinv*(hs_i + sum) ----
  k_gemm128<0><<<gGemm, 512, 0, stream>>>(x, W1, dinv, hs, N);
  k_agg<0><<<gN32, TPB, 0, stream>>>((float4*)out, hs, pay, off,
                                     cnt, dinv, (const float4*)b1, N);

  // ---- layer 2: hs = fp16(dinv*(relu(out)@W2)) ; out = relu(b2 + ...) ----
  k_gemm128<1><<<gGemm, 512, 0, stream>>>(out, W2, dinv, hs, N);
  k_agg<1><<<gN32, TPB, 0, stream>>>((float4*)out, hs, pay, off,
                                     cnt, dinv, (const float4*)b2, N);
}

// Round 8
// 230.574 us; speedup vs baseline: 2.4183x; 1.4808x over previous
//
#include <hip/hip_runtime.h>

#define TPB 256
#define CHA 16384   // edges per k_binA block

typedef _Float16 half_t;
typedef _Float16 half4 __attribute__((ext_vector_type(4)));   // 8 B
typedef _Float16 half8 __attribute__((ext_vector_type(8)));   // 16 B
typedef float f32x4 __attribute__((ext_vector_type(4)));

// ---------------- small utils ----------------

__global__ __launch_bounds__(TPB) void k_zero_i32(int* __restrict__ p, int n) {
  int i = blockIdx.x * TPB + threadIdx.x;
  if (i < n) p[i] = 0;
}

// ---------------- bucket-level histogram (bucket = dst >> 8) ---------------

__global__ __launch_bounds__(TPB) void k_bucket_hist(int* __restrict__ bc,
                                                     const int* __restrict__ ei,
                                                     long long E, int NB) {
  __shared__ int h[512];
  for (int i = threadIdx.x; i < 512; i += TPB) h[i] = 0;
  __syncthreads();
  long long stride = (long long)gridDim.x * TPB;
  for (long long e = (long long)blockIdx.x * TPB + threadIdx.x; e < E; e += stride)
    atomicAdd(&h[ei[E + e] >> 8], 1);
  __syncthreads();
  for (int i = threadIdx.x; i < NB; i += TPB)
    if (h[i]) atomicAdd(&bc[i], h[i]);
}

// exclusive scan of bc[NB] -> bbase[0..NB], bcursor = bbase (NB <= 512)
__global__ __launch_bounds__(512) void k_scan_buckets(int* __restrict__ bbase,
                                                      int* __restrict__ bcursor,
                                                      const int* __restrict__ bc,
                                                      int NB) {
  __shared__ int lds[512];
  int v = (threadIdx.x < NB) ? bc[threadIdx.x] : 0;
  lds[threadIdx.x] = v;
  __syncthreads();
  for (int ofs = 1; ofs < 512; ofs <<= 1) {
    int t = (threadIdx.x >= ofs) ? lds[threadIdx.x - ofs] : 0;
    __syncthreads();
    lds[threadIdx.x] += t;
    __syncthreads();
  }
  int excl = lds[threadIdx.x] - v;
  if (threadIdx.x < NB) { bbase[threadIdx.x] = excl; bcursor[threadIdx.x] = excl; }
  if (threadIdx.x == NB - 1) bbase[NB] = excl + v;
}

// ---------------- pass A: bin edges into buckets, LDS-staged ----------------
// key = (src << 8) | (dst & 255); runs written bucket-contiguously.
// 1024 threads: grid is only ~E/CHA blocks, so depth-per-thread matters.
__global__ __launch_bounds__(1024) void k_binA(unsigned* __restrict__ keys,
                                               int* __restrict__ bcursor,
                                               const int* __restrict__ ei,
                                               long long E, int NB) {
  __shared__ int hist[512];
  __shared__ int scanv[1024];
  __shared__ int base_run[512];
  __shared__ int bump[512];
  __shared__ unsigned stage[CHA];   // 64 KB

  const int tid = threadIdx.x;
  const long long e0 = (long long)blockIdx.x * CHA;
  const int cnt_here = (int)min((long long)CHA, E - e0);

  if (tid < 512) { hist[tid] = 0; bump[tid] = 0; }
  __syncthreads();

  for (int i = tid; i < cnt_here; i += 1024)
    atomicAdd(&hist[ei[E + e0 + i] >> 8], 1);
  __syncthreads();

  // exclusive scan of hist[512] (1024-slot scan, tail is harmless garbage)
  int v = (tid < 512) ? hist[tid] : 0;
  scanv[tid] = v;
  __syncthreads();
  for (int ofs = 1; ofs < 1024; ofs <<= 1) {
    int t = (tid >= ofs) ? scanv[tid - ofs] : 0;
    __syncthreads();
    scanv[tid] += t;
    __syncthreads();
  }
  int excl = scanv[tid] - v;
  __syncthreads();
  if (tid < 512) scanv[tid] = excl;
  // reserve global runs (one atomic per non-empty bucket)
  if (tid < NB) {
    int c = hist[tid];
    base_run[tid] = c ? atomicAdd(&bcursor[tid], c) : 0;
  }
  __syncthreads();

  // scatter into LDS stage, bucket-contiguous
  for (int i = tid; i < cnt_here; i += 1024) {
    int s = ei[e0 + i];
    int d = ei[E + e0 + i];
    int b = d >> 8;
    int r = atomicAdd(&bump[b], 1);
    stage[scanv[b] + r] = ((unsigned)s << 8) | (unsigned)(d & 255);
  }
  __syncthreads();

  // write runs coalesced: wave w takes buckets w, w+16, ...
  const int wave = tid >> 6, lane = tid & 63;
  for (int b = wave; b < NB; b += 16) {
    int s0 = scanv[b], c = hist[b], gbase = base_run[b];
    for (int j = lane; j < c; j += 64) keys[gbase + j] = stage[s0 + j];
  }
}

// ---------------- pass B: per-bucket counting sort + CSR emit ---------------
__global__ __launch_bounds__(TPB) void k_binB(int* __restrict__ pay,
                                              int* __restrict__ cnt,
                                              int* __restrict__ off,
                                              float* __restrict__ dinv,
                                              const unsigned* __restrict__ keys,
                                              const int* __restrict__ bbase,
                                              int N) {
  __shared__ int lcnt[256], lofs[256], lcur[256];
  const int tid = threadIdx.x;
  const int b = blockIdx.x;
  const int lo = bbase[b], hi = bbase[b + 1];

  lcnt[tid] = 0; lcur[tid] = 0;
  __syncthreads();
  for (int i = lo + tid; i < hi; i += TPB)
    atomicAdd(&lcnt[keys[i] & 255], 1);
  __syncthreads();

  int v = lcnt[tid];
  lofs[tid] = v;
  __syncthreads();
  for (int ofs = 1; ofs < 256; ofs <<= 1) {
    int t = (tid >= ofs) ? lofs[tid - ofs] : 0;
    __syncthreads();
    lofs[tid] += t;
    __syncthreads();
  }
  lofs[tid] -= v;   // exclusive
  __syncthreads();

  const int node = (b << 8) + tid;
  if (node < N) {
    cnt[node] = v;
    off[node] = lo + lofs[tid];
    dinv[node] = rsqrtf(1.0f + (float)v);
  }

  for (int i = lo + tid; i < hi; i += TPB) {
    unsigned k = keys[i];
    int l = (int)(k & 255u);
    int r = atomicAdd(&lcur[l], 1);
    pay[lo + lofs[l] + r] = (int)(k >> 8);
  }
}

// ------- W (f32 [128k][128n]) -> fp16 fragment-ordered Wf ------------------
// Wf layout: ((kc*8 + nt)*64 + lane)*8 + j, where n = nt*16 + (lane&15),
// k = kc*32 + (lane>>4)*8 + j.  (B-operand layout of mfma_f32_16x16x32_f16)
__global__ __launch_bounds__(TPB) void k_prepW(half_t* __restrict__ Wf,
                                               const float* __restrict__ W) {
  int f = blockIdx.x * TPB + threadIdx.x;   // 0..4095, one half4 each
  if (f >= 4096) return;
  int j0 = (f & 1) * 4;
  int lane = (f >> 1) & 63;
  int nt = (f >> 7) & 7;
  int kc = f >> 10;
  int n = nt * 16 + (lane & 15);
  int kb = kc * 32 + ((lane >> 4) << 3) + j0;
  half4 o;
  o.x = (_Float16)W[(kb + 0) * 128 + n];
  o.y = (_Float16)W[(kb + 1) * 128 + n];
  o.z = (_Float16)W[(kb + 2) * 128 + n];
  o.w = (_Float16)W[(kb + 3) * 128 + n];
  *(half4*)&Wf[f * 4] = o;
}

// ---------- MFMA GEMM: hs[N,128](fp16) = dinv * (A[N,128] @ W[128,128]) -----
// 64-row tile, 256 threads (4 waves), wave rg owns rows rg*16..+15.
// As/Ws fragment-ordered in LDS; linear half8 access = conflict-free.
// mfma_f32_16x16x32_f16: A m=lane&15,k=(lane>>4)*8+j; B n=lane&15,same k;
// C col=lane&15, row=(lane>>4)*4+reg  [m89-verified family].
template <int AF16>
__global__ __launch_bounds__(TPB) void k_gemm_mfma(const void* __restrict__ Ain,
                                                   const half_t* __restrict__ Wf,
                                                   const float* __restrict__ dinv,
                                                   half_t* __restrict__ hs, int N) {
  __shared__ half_t As[64 * 128];   // 16 KB, slot s=(rg*4+kc)*64+lane
  __shared__ half_t Ws[16384];      // 32 KB, slot (kc*8+nt)*64+lane
  const int tid = threadIdx.x;
  const long long row0 = (long long)blockIdx.x * 64;

  { // stage Ws: flat coalesced copy
    half8* d = (half8*)Ws;
    const half8* s = (const half8*)Wf;
#pragma unroll
    for (int i = 0; i < 8; ++i) d[i * 256 + tid] = s[i * 256 + tid];
  }
  { // stage A fragment-ordered (slot-linear LDS writes: conflict-free)
#pragma unroll
    for (int i = 0; i < 4; ++i) {
      int s = i * 256 + tid;          // 0..1023
      int lane6 = s & 63;
      int grp = s >> 6;               // rg*4 + kc
      int rg = grp >> 2, kc = grp & 3;
      int m = lane6 & 15, kg = lane6 >> 4;
      long long gr = row0 + rg * 16 + m;
      half8 hv = {};
      if (gr < (long long)N) {
        if (AF16) {
          hv = ((const half8*)Ain)[gr * 16 + kc * 4 + kg];
        } else {
          const float4* A4 = (const float4*)Ain;
          float4 v0 = A4[gr * 32 + kc * 8 + kg * 2];
          float4 v1 = A4[gr * 32 + kc * 8 + kg * 2 + 1];
          hv[0] = (_Float16)v0.x; hv[1] = (_Float16)v0.y;
          hv[2] = (_Float16)v0.z; hv[3] = (_Float16)v0.w;
          hv[4] = (_Float16)v1.x; hv[5] = (_Float16)v1.y;
          hv[6] = (_Float16)v1.z; hv[7] = (_Float16)v1.w;
        }
      }
      ((half8*)As)[s] = hv;
    }
  }
  __syncthreads();

  const int rg = tid >> 6, lane = tid & 63;
  f32x4 acc[8];
#pragma unroll
  for (int nt = 0; nt < 8; ++nt) {
    f32x4 z = {0.f, 0.f, 0.f, 0.f};
    acc[nt] = z;
  }
#pragma unroll
  for (int kc = 0; kc < 4; ++kc) {
    half8 a = ((const half8*)As)[(rg * 4 + kc) * 64 + lane];
#pragma unroll
    for (int nt = 0; nt < 8; ++nt) {
      half8 b = ((const half8*)Ws)[(kc * 8 + nt) * 64 + lane];
      acc[nt] = __builtin_amdgcn_mfma_f32_16x16x32_f16(a, b, acc[nt], 0, 0, 0);
    }
  }

  // epilogue: scale by dinv, cvt fp16, store (lanes 0-15 cover 32B runs)
  const int ncol = lane & 15;
  const int mbase = (lane >> 4) << 2;
#pragma unroll
  for (int r = 0; r < 4; ++r) {
    long long grow = row0 + rg * 16 + mbase + r;
    if (grow < (long long)N) {
      float sc = dinv[grow];
      half_t* dst = &hs[grow * 128 + ncol];
#pragma unroll
      for (int nt = 0; nt < 8; ++nt)
        dst[nt * 16] = (_Float16)(acc[nt][r] * sc);
    }
  }
}

// ---------------- gather-reduce aggregation (no atomics) --------------------
// out[i,:] = relu( b + dinv[i] * ( hs[i,:] + sum_{e: dst=i} hs[src,:] ) )
// 32-lane group per node; hs rows fp16 (256B), half4 per lane; f32 accum.
template <int OUTF16>
__global__ __launch_bounds__(TPB) void k_agg(void* __restrict__ outp,
                                             const half4* __restrict__ hs,
                                             const int* __restrict__ pay,
                                             const int* __restrict__ off,
                                             const int* __restrict__ cnt,
                                             const float* __restrict__ dinv,
                                             const float4* __restrict__ b, int N) {
  long long t = (long long)blockIdx.x * TPB + threadIdx.x;
  int g = (int)(t >> 5);
  if (g >= N) return;
  int c = (int)(t & 31);
  float di = dinv[g];
  float4 bv = b[c];

  half4 hv = hs[(long long)g * 32 + c];   // self-loop term (prescaled)
  float4 acc;
  acc.x = (float)hv.x; acc.y = (float)hv.y;
  acc.z = (float)hv.z; acc.w = (float)hv.w;

  int p = off[g];
  const int en = p + cnt[g];

  for (; p + 8 <= en; p += 8) {
    int s[8];
#pragma unroll
    for (int u = 0; u < 8; ++u) s[u] = pay[p + u];
    half4 v[8];
#pragma unroll
    for (int u = 0; u < 8; ++u) v[u] = hs[(long long)s[u] * 32 + c];
#pragma unroll
    for (int u = 0; u < 8; ++u) {
      acc.x += (float)v[u].x; acc.y += (float)v[u].y;
      acc.z += (float)v[u].z; acc.w += (float)v[u].w;
    }
  }
  if (p + 4 <= en) {
    int s[4];
#pragma unroll
    for (int u = 0; u < 4; ++u) s[u] = pay[p + u];
    half4 v[4];
#pragma unroll
    for (int u = 0; u < 4; ++u) v[u] = hs[(long long)s[u] * 32 + c];
#pragma unroll
    for (int u = 0; u < 4; ++u) {
      acc.x += (float)v[u].x; acc.y += (float)v[u].y;
      acc.z += (float)v[u].z; acc.w += (float)v[u].w;
    }
    p += 4;
  }
  for (; p < en; ++p) {
    half4 v = hs[(long long)pay[p] * 32 + c];
    acc.x += (float)v.x; acc.y += (float)v.y;
    acc.z += (float)v.z; acc.w += (float)v.w;
  }

  float4 o;
  o.x = fmaxf(fmaf(acc.x, di, bv.x), 0.f);
  o.y = fmaxf(fmaf(acc.y, di, bv.y), 0.f);
  o.z = fmaxf(fmaf(acc.z, di, bv.z), 0.f);
  o.w = fmaxf(fmaf(acc.w, di, bv.w), 0.f);

  if (OUTF16) {
    half4 ho;
    ho.x = (_Float16)o.x; ho.y = (_Float16)o.y;
    ho.z = (_Float16)o.z; ho.w = (_Float16)o.w;
    ((half4*)outp)[(long long)g * 32 + c] = ho;
  } else {
    ((float4*)outp)[(long long)g * 32 + c] = o;
  }
}

// ---------------------------------------------------------------------------

extern "C" void kernel_launch(void* const* d_in, const int* in_sizes, int n_in,
                              void* d_out, int out_size, void* d_ws, size_t ws_size,
                              hipStream_t stream) {
  const float* x  = (const float*)d_in[0];
  const float* W1 = (const float*)d_in[1];
  const float* b1 = (const float*)d_in[2];
  const float* W2 = (const float*)d_in[3];
  const float* b2 = (const float*)d_in[4];
  const int*   ei = (const int*)d_in[5];   // [2,E] int32

  const int N = in_sizes[0] / 128;
  const long long E = in_sizes[5] / 2;
  const int NB = (N + 255) >> 8;           // buckets of 256 nodes (<= 512)

  // ws layout (16B alignment preserved: all sizes multiples of 16)
  char* w = (char*)d_ws;
  half_t*   hs      = (half_t*)w;          w += (size_t)N * 128 * 2;
  half_t*   a1h     = (half_t*)w;          w += (size_t)N * 128 * 2;
  int*      pay     = (int*)w;             w += (size_t)E * 4;
  unsigned* keys    = (unsigned*)w;        w += (size_t)E * 4;
  int*      cnt     = (int*)w;             w += (size_t)N * 4;
  int*      off     = (int*)w;             w += (size_t)N * 4;
  float*    dinv    = (float*)w;           w += (size_t)N * 4;
  half_t*   Wf1     = (half_t*)w;          w += 16384 * 2;
  half_t*   Wf2     = (half_t*)w;          w += 16384 * 2;
  int*      bc      = (int*)w;             w += (size_t)NB * 4;
  int*      bbase   = (int*)w;             w += (size_t)(NB + 1) * 4;
  int*      bcursor = (int*)w;

  float* out = (float*)d_out;

  const long long n32 = (long long)N * 32;
  const int gN32 = (int)((n32 + TPB - 1) / TPB);
  const int gGemm = (N + 63) / 64;
  const int gBinA = (int)((E + CHA - 1) / CHA);

  // ---- W -> fp16 fragment order (independent of sort) ----
  k_prepW<<<16, TPB, 0, stream>>>(Wf1, W1);
  k_prepW<<<16, TPB, 0, stream>>>(Wf2, W2);

  // ---- binned counting sort by dst + CSR/dinv emit ----
  k_zero_i32<<<(NB + TPB - 1) / TPB, TPB, 0, stream>>>(bc, NB);
  k_bucket_hist<<<1024, TPB, 0, stream>>>(bc, ei, E, NB);
  k_scan_buckets<<<1, 512, 0, stream>>>(bbase, bcursor, bc, NB);
  k_binA<<<gBinA, 1024, 0, stream>>>(keys, bcursor, ei, E, NB);
  k_binB<<<NB, TPB, 0, stream>>>(pay, cnt, off, dinv, keys, bbase, N);

  // ---- layer 1: hs = fp16(dinv*(x@W1)); a1h = fp16(relu(b1 + dinv*agg)) ----
  k_gemm_mfma<0><<<gGemm, TPB, 0, stream>>>(x, Wf1, dinv, hs, N);
  k_agg<1><<<gN32, TPB, 0, stream>>>(a1h, (const half4*)hs, pay, off,
                                     cnt, dinv, (const float4*)b1, N);

  // ---- layer 2: hs = fp16(dinv*(a1h@W2)); out = relu(b2 + dinv*agg) ----
  k_gemm_mfma<1><<<gGemm, TPB, 0, stream>>>(a1h, Wf2, dinv, hs, N);
  k_agg<0><<<gN32, TPB, 0, stream>>>(out, (const half4*)hs, pay, off,
                                     cnt, dinv, (const float4*)b2, N);
}